// Round 9
// baseline (70.637 us; speedup 1.0000x reference)
//
#include <hip/hip_runtime.h>

#define OUT_F 16384
#define IN_F  4096
#define BATCH 32
#define GS    128
#define NG    32
#define KT    128          // ints per row per K-tile (== GS)
#define NT    32           // IN_F / KT

typedef __attribute__((ext_vector_type(4)))  int    int4v;
typedef __attribute__((ext_vector_type(8)))  short  short8v;
typedef __attribute__((ext_vector_type(16))) float  floatx16;

// f32 -> bf16 round-to-nearest-even (bit-level)
static __device__ __forceinline__ short f32_bf16_rne(float f) {
    unsigned u = __float_as_uint(f);
    u += 0x7FFFu + ((u >> 16) & 1u);
    return (short)(u >> 16);
}

// HBM -> LDS direct, 16B/lane; dest = wave-uniform base + lane*16 (HW rule)
#define GLOAD_LDS16(gp, lp)                                                    \
    __builtin_amdgcn_global_load_lds(                                          \
        (const __attribute__((address_space(1))) void*)(gp),                   \
        (__attribute__((address_space(3))) void*)(lp), 16, 0, 0)

// ---------------------------------------------------------------------------
// Pre-kernel: x B-fragments in MFMA layout (verified rounds 5-6).
// Lane l of chunk c holds x[b = l&31][k = c*16 + (l>>5)*8 + i], i=0..7.
// ---------------------------------------------------------------------------
__global__ void xfrag_kernel(const float* __restrict__ x, short* __restrict__ xf) {
    int gid = blockIdx.x * blockDim.x + threadIdx.x;  // 0..131071
    int i = gid & 7;
    int l = (gid >> 3) & 63;
    int c = gid >> 9;
    int b = l & 31;
    int k = c * 16 + (l >> 5) * 8 + i;
    xf[gid] = f32_bf16_rne(x[(size_t)b * IN_F + k]);
}

// ---------------------------------------------------------------------------
// Main kernel: 512 blocks x 1 wave. Wave owns 32 output rows x full K.
// Per K-tile [32 rows][128 ints]: 16x global_load_lds (1 KB each, global
// source pre-swizzled u^row so LDS is XOR-swizzled), double-buffered,
// counted vmcnt(16) -- NO barriers, queue never drains until the last tile.
// 8 chunks/tile: 2x swizzled ds_read_b128 + dequant + mfma_32x32x16_bf16.
// Wave-local epilogue: XOR'd LDS transpose -> coalesced stores + bias.
// ---------------------------------------------------------------------------
__global__ __launch_bounds__(64) void int4linear_mfma(
    const int* __restrict__ w, const float* __restrict__ scales,
    const float* __restrict__ bias, const short* __restrict__ xf,
    float* __restrict__ out)
{
    __shared__ int lds[2 * 32 * KT];   // 32 KB double buffer

    const int l  = threadIdx.x;        // 0..63
    const int ll = l & 31;
    const int hl = l >> 5;
    const int o_base = blockIdx.x * 32;

    floatx16 acc = {};

    // per-lane global int-offsets for the 16 staging instrs (lane-constant):
    // instr j covers rows r = 2j+hl; fetches logical unit u = ll ^ r so that
    // the linear gload_lds write leaves LDS[r][p] = logical unit p ^ r.
    int goff[16];
#pragma unroll
    for (int j = 0; j < 16; ++j) {
        int r = 2 * j + hl;
        int u = ll ^ r;
        goff[j] = (o_base + r) * IN_F + u * 4;
    }

    // prologue: stage tile 0 into buffer 0
#pragma unroll
    for (int j = 0; j < 16; ++j)
        GLOAD_LDS16(w + goff[j], &lds[j * 256]);

    for (int t = 0; t < NT; ++t) {
        const int rbuf = (t & 1) * (32 * KT);
        const int wbuf = ((t + 1) & 1) * (32 * KT);

        // B fragments for this tile (xf is L2/L3-hot)
        short8v bfr[8];
#pragma unroll
        for (int ch = 0; ch < 8; ++ch)
            bfr[ch] = *(const short8v*)(xf + (size_t)((t * 8 + ch) * 64 + l) * 8);

        // issue next tile's 16 loads, then counted wait: tile t's loads (and
        // the bf loads) complete, tile t+1's 16 stay in flight.
        if (t + 1 < NT) {
#pragma unroll
            for (int j = 0; j < 16; ++j)
                GLOAD_LDS16(w + goff[j] + (t + 1) * KT, &lds[wbuf + j * 256]);
            asm volatile("s_waitcnt vmcnt(16)" ::: "memory");
        } else {
            asm volatile("s_waitcnt vmcnt(0)" ::: "memory");
        }
        __builtin_amdgcn_sched_barrier(0);

        // KT == GS: exactly one scale per (row, tile)
        const float sc = scales[(size_t)(o_base + ll) * NG + t];

#pragma unroll
        for (int ch = 0; ch < 8; ++ch) {
            const int u0 = ch * 4 + hl * 2;   // logical 16B-unit in row ll
            const int4v qa = *(const int4v*)&lds[rbuf + ll * KT + (((u0    ) ^ ll) << 2)];
            const int4v qb = *(const int4v*)&lds[rbuf + ll * KT + (((u0 + 1) ^ ll) << 2)];

            short8v af;
            af[0] = f32_bf16_rne((float)qa[0] * sc);
            af[1] = f32_bf16_rne((float)qa[1] * sc);
            af[2] = f32_bf16_rne((float)qa[2] * sc);
            af[3] = f32_bf16_rne((float)qa[3] * sc);
            af[4] = f32_bf16_rne((float)qb[0] * sc);
            af[5] = f32_bf16_rne((float)qb[1] * sc);
            af[6] = f32_bf16_rne((float)qb[2] * sc);
            af[7] = f32_bf16_rne((float)qb[3] * sc);

            acc = __builtin_amdgcn_mfma_f32_32x32x16_bf16(af, bfr[ch], acc, 0, 0, 0);
        }
    }

    // ---- wave-local epilogue: XOR'd LDS transpose -> coalesced stores ----
    float* lf = (float*)lds;   // buffer 0 region, all loads drained
#pragma unroll
    for (int r = 0; r < 16; ++r) {
        // C/D layout (verified): b = lane&31, o = (r&3)+8*(r>>2)+4*(lane>>5)
        int o = (r & 3) + 8 * (r >> 2) + 4 * hl;
        lf[o * 32 + (ll ^ o)] = acc[r];     // conflict-free (XOR bijection)
    }
    asm volatile("s_waitcnt lgkmcnt(0)" ::: "memory");
    __builtin_amdgcn_sched_barrier(0);

    const float bv = bias[o_base + ll];
#pragma unroll
    for (int i = 0; i < 16; ++i) {
        int b = 2 * i + hl;
        float v = lf[ll * 32 + (b ^ ll)];   // conflict-free
        out[(size_t)b * OUT_F + o_base + ll] = v + bv;  // 128B runs, coalesced
    }
}

extern "C" void kernel_launch(void* const* d_in, const int* in_sizes, int n_in,
                              void* d_out, int out_size, void* d_ws, size_t ws_size,
                              hipStream_t stream) {
    const float* x      = (const float*)d_in[0];
    const int*   w      = (const int*)d_in[1];
    const float* scales = (const float*)d_in[2];
    const float* bias   = (const float*)d_in[3];
    float*       out    = (float*)d_out;
    short*       xfrag  = (short*)d_ws;  // 256 KB fragment buffer

    hipLaunchKernelGGL(xfrag_kernel, dim3(512), dim3(256), 0, stream, x, xfrag);
    hipLaunchKernelGGL(int4linear_mfma, dim3(OUT_F / 32), dim3(64), 0, stream,
                       w, scales, bias, xfrag, out);
}

// Round 11
// 52.452 us; speedup vs baseline: 1.3467x; 1.3467x over previous
//
#include <hip/hip_runtime.h>

#define OUT_F 16384
#define IN_F  4096
#define BATCH 32
#define GS    128
#define NG    32
#define KT    128          // ints per row per K-tile (== GS)
#define NTW   16           // tiles per wave (half-K: 2048 ints / KT)

typedef __attribute__((ext_vector_type(4)))  int    int4v;
typedef __attribute__((ext_vector_type(4)))  float  float4v;
typedef __attribute__((ext_vector_type(8)))  short  short8v;
typedef __attribute__((ext_vector_type(16))) float  floatx16;

// f32 -> bf16 round-to-nearest-even (bit-level)
static __device__ __forceinline__ short f32_bf16_rne(float f) {
    unsigned u = __float_as_uint(f);
    u += 0x7FFFu + ((u >> 16) & 1u);
    return (short)(u >> 16);
}

// HBM -> LDS direct, 16B/lane; dest = wave-uniform base + lane*16 (HW rule)
#define GLOAD_LDS16(gp, lp)                                                    \
    __builtin_amdgcn_global_load_lds(                                          \
        (const __attribute__((address_space(1))) void*)(gp),                   \
        (__attribute__((address_space(3))) void*)(lp), 16, 0, 0)

// ---------------------------------------------------------------------------
// Pre-kernel: x B-fragments in MFMA layout (verified rounds 5-9).
// Lane l of chunk c holds x[b = l&31][k = c*16 + (l>>5)*8 + i], i=0..7.
// ---------------------------------------------------------------------------
__global__ void xfrag_kernel(const float* __restrict__ x, short* __restrict__ xf) {
    int gid = blockIdx.x * blockDim.x + threadIdx.x;  // 0..131071
    int i = gid & 7;
    int l = (gid >> 3) & 63;
    int c = gid >> 9;
    int b = l & 31;
    int k = c * 16 + (l >> 5) * 8 + i;
    xf[gid] = f32_bf16_rne(x[(size_t)b * IN_F + k]);
}

// ---------------------------------------------------------------------------
// Main kernel: 512 blocks x 2 waves. Wave wv owns 32 rows x half-K
// (16 tiles of [32 rows][128 ints]); waves' LDS regions are private ->
// NO main-loop barriers. Per tile: 16x global_load_lds (1 KB, source
// pre-swizzled), xf prefetched ONE TILE AHEAD into bfrA/bfrB, counted
// vmcnt(24) = drain last tile's 24 ops only (queue never empties).
// Epilogue: 2-wave LDS reduce, then verified XOR-transpose + bias store.
// ---------------------------------------------------------------------------
__global__ __launch_bounds__(128) void int4linear_mfma(
    const int* __restrict__ w, const float* __restrict__ scales,
    const float* __restrict__ bias, const short* __restrict__ xf,
    float* __restrict__ out)
{
    __shared__ int lds[16384];         // 64 KB: wave wv owns [wv*8192, +8192)

    const int tid = threadIdx.x;
    const int wv  = tid >> 6;          // 0..1
    const int l   = tid & 63;
    const int ll  = l & 31;
    const int hl  = l >> 5;
    const int o_base = blockIdx.x * 32;

    floatx16 acc = {};
    int* mylds = lds + wv * 8192;

    // staging addresses (ints): instr j covers rows r = 2j+hl; source unit
    // u = ll ^ r so the linear gload_lds write leaves LDS[r][slot s] = unit s^r.
    int goff[16];
#pragma unroll
    for (int j = 0; j < 16; ++j) {
        int r = 2 * j + hl;
        int u = ll ^ r;
        goff[j] = (o_base + r) * IN_F + wv * 2048 + u * 4;
    }

    // preload this wave's 16 group-scales for row ll (no per-tile VMEM)
    float scv[16];
    {
        const float* sp = scales + (size_t)(o_base + ll) * NG + wv * 16;
#pragma unroll
        for (int j = 0; j < 4; ++j) {
            float4v v = *(const float4v*)(sp + 4 * j);
            scv[4 * j + 0] = v[0]; scv[4 * j + 1] = v[1];
            scv[4 * j + 2] = v[2]; scv[4 * j + 3] = v[3];
        }
    }

    const short* xfw = xf + (size_t)(wv * 128) * 512;   // wave's chunk base

    short8v bfrA[8], bfrB[8];

    // ---- prologue: stage tile 0 + xf tile 0 ----
#pragma unroll
    for (int j = 0; j < 16; ++j)
        GLOAD_LDS16(w + goff[j], &mylds[j * 256]);
#pragma unroll
    for (int ch = 0; ch < 8; ++ch)
        bfrA[ch] = *(const short8v*)(xfw + (size_t)ch * 512 + l * 8);

#pragma unroll
    for (int t = 0; t < NTW; ++t) {
        const int rbuf = (t & 1) * 4096;
        const int wbuf = ((t + 1) & 1) * 4096;

        if (t + 1 < NTW) {
            // issue next tile's staging, then next tile's xf (prefetch)
#pragma unroll
            for (int j = 0; j < 16; ++j)
                GLOAD_LDS16(w + goff[j] + (t + 1) * KT, &mylds[wbuf + j * 256]);
#pragma unroll
            for (int ch = 0; ch < 8; ++ch) {
                short8v v = *(const short8v*)(xfw + (size_t)((t + 1) * 8 + ch) * 512 + l * 8);
                if (t & 1) bfrA[ch] = v; else bfrB[ch] = v;
            }
            // drain exactly last iteration's 24 ops (issued a full tile ago);
            // keep the newest 24 (staging t+1 + xf t+1) in flight.
            asm volatile("s_waitcnt vmcnt(24)" ::: "memory");
        } else {
            asm volatile("s_waitcnt vmcnt(0)" ::: "memory");
        }
        __builtin_amdgcn_sched_barrier(0);

        const float sc = scv[t];

#pragma unroll
        for (int ch = 0; ch < 8; ++ch) {
            const int u0 = ch * 4 + hl * 2;   // logical 16B-unit in row ll
            const int4v qa = *(const int4v*)&mylds[rbuf + ll * KT + (((u0    ) ^ ll) << 2)];
            const int4v qb = *(const int4v*)&mylds[rbuf + ll * KT + (((u0 + 1) ^ ll) << 2)];
            const short8v bf = (t & 1) ? bfrB[ch] : bfrA[ch];

            short8v af;
            af[0] = f32_bf16_rne((float)qa[0] * sc);
            af[1] = f32_bf16_rne((float)qa[1] * sc);
            af[2] = f32_bf16_rne((float)qa[2] * sc);
            af[3] = f32_bf16_rne((float)qa[3] * sc);
            af[4] = f32_bf16_rne((float)qb[0] * sc);
            af[5] = f32_bf16_rne((float)qb[1] * sc);
            af[6] = f32_bf16_rne((float)qb[2] * sc);
            af[7] = f32_bf16_rne((float)qb[3] * sc);

            acc = __builtin_amdgcn_mfma_f32_32x32x16_bf16(af, bf, acc, 0, 0, 0);
        }
    }

    // ---- epilogue: 2-wave k-reduce, then verified XOR-transpose store ----
    if (wv == 1) {
        float* red = (float*)(lds + 8192);
#pragma unroll
        for (int r = 0; r < 16; ++r)
            red[l * 16 + r] = acc[r];       // b128 writes, 2-way (free)
    }
    __syncthreads();
    if (wv == 0) {
        const float* red = (const float*)(lds + 8192);
#pragma unroll
        for (int r = 0; r < 16; ++r)
            acc[r] += red[l * 16 + r];

        float* lf = (float*)lds;
#pragma unroll
        for (int r = 0; r < 16; ++r) {
            // C/D layout (verified): b = lane&31, o = (r&3)+8*(r>>2)+4*(lane>>5)
            int o = (r & 3) + 8 * (r >> 2) + 4 * hl;
            lf[o * 32 + (ll ^ o)] = acc[r]; // conflict-free (XOR bijection)
        }
        asm volatile("s_waitcnt lgkmcnt(0)" ::: "memory");
        __builtin_amdgcn_sched_barrier(0);

        const float bv = bias[o_base + ll];
#pragma unroll
        for (int i = 0; i < 16; ++i) {
            int b = 2 * i + hl;
            float v = lf[ll * 32 + (b ^ ll)];            // conflict-free
            out[(size_t)b * OUT_F + o_base + ll] = v + bv; // 128B-coalesced
        }
    }
}

extern "C" void kernel_launch(void* const* d_in, const int* in_sizes, int n_in,
                              void* d_out, int out_size, void* d_ws, size_t ws_size,
                              hipStream_t stream) {
    const float* x      = (const float*)d_in[0];
    const int*   w      = (const int*)d_in[1];
    const float* scales = (const float*)d_in[2];
    const float* bias   = (const float*)d_in[3];
    float*       out    = (float*)d_out;
    short*       xfrag  = (short*)d_ws;  // 256 KB fragment buffer

    hipLaunchKernelGGL(xfrag_kernel, dim3(512), dim3(256), 0, stream, x, xfrag);
    hipLaunchKernelGGL(int4linear_mfma, dim3(OUT_F / 32), dim3(128), 0, stream,
                       w, scales, bias, xfrag, out);
}